// Round 5
// baseline (261.995 us; speedup 1.0000x reference)
//
#include <hip/hip_runtime.h>
#include <math.h>

// GoBERT: GATConv(4x32) -> BN -> GCNConv(128) -> BN -> GlobalAttention -> FC
// Round 11: two nodes per wave in the aggregation kernels.
//  R10 post-mortem: pipeline now memset+6 launches, ~140us controllable
//  (the 256MB harness poison fills appear to sit inside the measured window
//  as a fixed ~87us floor). Aggr kernels remain the largest controllable
//  item and are latency-bound (R8/R9 evidence): one node per wave exposes
//  the full csr->aSg->exp->lds->gather serial chain per node.
//  - gat/gcn aggr: 2 nodes/wave (16/block, 3125 blocks); two independent
//    staging chains interleave; combined gather stream runs through a
//    4-buffer software pipeline (static buffer names, no runtime indexing).
//  - __launch_bounds__(512,4) pins VGPR<=128 -> guaranteed 2 blocks/CU.
// prep/gemm/binB/pool unchanged from R10.

#define NEG_SLOPE 0.2f
#define BKT_BITS 7
#define BKT_SIZE 128
#define CHUNK_A 2048
#define BCAP 4096

typedef __attribute__((ext_vector_type(8))) short short8v;
typedef __attribute__((ext_vector_type(4))) float floatx4;

__device__ __forceinline__ int lower_bound_i(const int* a, int n, int key) {
    int lo = 0, hi = n;
    while (lo < hi) {
        int mid = (lo + hi) >> 1;
        if (a[mid] < key) lo = mid + 1; else hi = mid;
    }
    return lo;
}

__device__ __forceinline__ unsigned pack_bf16(float lo, float hi) {
    unsigned ua = __float_as_uint(lo);
    unsigned ub = __float_as_uint(hi);
    ua = ua + 0x7fffu + ((ua >> 16) & 1u);
    ub = ub + 0x7fffu + ((ub >> 16) & 1u);
    return (ua >> 16) | (ub & 0xffff0000u);
}

__device__ __forceinline__ unsigned short bf16_1(float v) {
    unsigned u = __float_as_uint(v);
    u = u + 0x7fffu + ((u >> 16) & 1u);
    return (unsigned short)(u >> 16);
}

// ---------------- prep: weight transpose (blocks 0-1) || binA (rest) -------
__global__ __launch_bounds__(256) void k_prep(
    const float* __restrict__ W1, const float* __restrict__ atts,
    const float* __restrict__ attd, const float* __restrict__ W2,
    unsigned short* __restrict__ Wt1, unsigned short* __restrict__ Wt2,
    const int* __restrict__ ei, int* __restrict__ bcur,
    int2* __restrict__ pairs, int E, int NB)
{
    __shared__ float sW[128 * 129];          // 64.5KB; aliased by binA branch
    const int b = blockIdx.x;
    const int tid = threadIdx.x;
    if (b < 2) {
        const float* W = b ? W2 : W1;
        unsigned short* Wt = b ? Wt2 : Wt1;
        for (int t = tid; t < 128 * 128; t += 256)
            sW[(t >> 7) * 129 + (t & 127)] = W[t];   // coalesced global read
        __syncthreads();
        const int lim = b ? (128 * 128) : (144 * 128);
        for (int idx = tid; idx < lim; idx += 256) {
            int j = idx >> 7, i = idx & 127;
            float v;
            if (j < 128) v = sW[i * 129 + j];        // lanes vary i: no conflict
            else if (j < 132) {
                int h = j - 128; float s = 0.f;
                for (int c = 0; c < 32; c++) s += sW[i * 129 + h * 32 + c] * atts[h * 32 + c];
                v = s;
            } else if (j < 136) {
                int h = j - 132; float s = 0.f;
                for (int c = 0; c < 32; c++) s += sW[i * 129 + h * 32 + c] * attd[h * 32 + c];
                v = s;
            } else v = 0.f;
            Wt[idx] = bf16_1(v);
        }
    } else {
        int* h    = (int*)sW;                // [512]
        int* base = h + 512;                 // [512]
        for (int i = tid; i < NB + 1; i += 256) h[i] = 0;
        __syncthreads();
        const int c0 = (b - 2) * CHUNK_A;
        int s[8], d[8], bk[8];
#pragma unroll
        for (int k = 0; k < 8; k++) {
            int e = c0 + k * 256 + tid;
            bool v = e < E;
            s[k] = v ? ei[e] : 0;
            d[k] = v ? ei[E + e] : 0;
            bk[k] = v ? (d[k] >> BKT_BITS) : NB;
            atomicAdd(&h[bk[k]], 1);
        }
        __syncthreads();
        for (int i = tid; i < NB + 1; i += 256) {
            int c = h[i];
            base[i] = c ? atomicAdd(&bcur[i], c) : 0;
            h[i] = 0;
        }
        __syncthreads();
#pragma unroll
        for (int k = 0; k < 8; k++) {
            int r = atomicAdd(&h[bk[k]], 1);
            pairs[(size_t)bk[k] * BCAP + base[bk[k]] + r] = make_int2(s[k], d[k]);
        }
    }
}

// ---------------- MFMA GEMM: 128 rows/block, Cb[N,64 pairs] ----------------
// MODE 0 launch also hosts binB in blocks >= gemmBlocks (independent work).
template<int MODE>
__global__ __launch_bounds__(256) void k_gemm_mfma(
    const void* __restrict__ Ain, const unsigned short* __restrict__ Wt,
    unsigned* __restrict__ Cb, int N,
    const float* __restrict__ pb, const float* __restrict__ pw,
    const float* __restrict__ pb2, const float* __restrict__ dinv,
    float* __restrict__ aS, float* __restrict__ aD,
    const int2* __restrict__ pairs, const int* __restrict__ bcnt,
    int* __restrict__ csr, int* __restrict__ offs, int* __restrict__ deg,
    float* __restrict__ dinvw, int gemmBlocks)
{
    constexpr int NCT = (MODE == 0) ? 9 : 8;
    __shared__ unsigned short sA[128 * 136];
    __shared__ unsigned short sB[NCT * 16 * 136];
    const int tid = threadIdx.x;

    if (MODE == 0 && (int)blockIdx.x >= gemmBlocks) {
        // ---------------- binB: bucket -> padded CSR ----------------
        __shared__ int wtot;
        int* hist  = (int*)sA;               // [128]
        int* start = hist + 128;             // [128]
        int* cur   = start + 128;            // [128]
        const int b = blockIdx.x - gemmBlocks;
        const int lane = tid & 63;
        const int d0 = b << BKT_BITS;
        const size_t pbg = (size_t)b * BCAP;
        const int cntb = bcnt[b];
        if (tid < BKT_SIZE) { hist[tid] = 0; cur[tid] = 0; }
        __syncthreads();
        for (int i = tid; i < cntb; i += 256)
            atomicAdd(&hist[pairs[pbg + i].y - d0], 1);
        __syncthreads();
        int own = (tid < BKT_SIZE) ? hist[tid] : 0;
        int incl = own;
#pragma unroll
        for (int st = 1; st < 64; st <<= 1) {
            int t = __shfl_up(incl, st);
            if (lane >= st) incl += t;
        }
        if (tid == 63) wtot = incl;          // wave-0 total
        __syncthreads();
        if (tid < BKT_SIZE) {
            if (tid >= 64) incl += wtot;
            int abs0 = (int)pbg + (incl - own);
            start[tid] = abs0;
            int dd = d0 + tid;
            if (dd < N) {
                offs[dd] = abs0;
                deg[dd] = own;
                dinvw[dd] = rsqrtf((float)(own + 1));
            }
        }
        __syncthreads();
        for (int i = tid; i < cntb; i += 256) {
            int2 p = pairs[pbg + i];
            int ld = p.y - d0;
            int r = atomicAdd(&cur[ld], 1);
            csr[start[ld] + r] = p.x;
        }
        return;
    }

    const int n0 = blockIdx.x * 128;

    // stage B (coalesced uint4, LDS row stride 136)
    {
        const uint4* Wg = (const uint4*)Wt;
        const int nq = NCT * 16 * 16;
        for (int q = tid; q < nq; q += 256) {
            uint4 v = Wg[q];
            int j = q >> 4, seg = q & 15;
            *(uint4*)(sB + j * 136 + seg * 8) = v;
        }
    }
    // stage A
    if (MODE == 0) {
        const float* A = (const float*)Ain;
        const int w4 = tid & 31;          // float4 within row
        const int r0 = tid >> 5;          // 0..7
#pragma unroll
        for (int i = 0; i < 16; i++) {
            int r = r0 + 8 * i;
            int gn = n0 + r;
            unsigned p0 = 0, p1 = 0;
            if (gn < N) {
                float4 v = *(const float4*)(A + (size_t)gn * 128 + w4 * 4);
                p0 = pack_bf16(v.x, v.y);
                p1 = pack_bf16(v.z, v.w);
            }
            *(uint2*)(sA + r * 136 + w4 * 4) = make_uint2(p0, p1);
        }
    } else {
        const unsigned short* A = (const unsigned short*)Ain;
        const int w8 = tid & 15;          // 8-channel group within row
        const int r0 = tid >> 4;          // 0..15
        const int k0 = w8 * 8;
        float pbv[8], pwv[8], p2v[8];
        *(float4*)(pbv)     = *(const float4*)(pb + k0);
        *(float4*)(pbv + 4) = *(const float4*)(pb + k0 + 4);
        *(float4*)(pwv)     = *(const float4*)(pw + k0);
        *(float4*)(pwv + 4) = *(const float4*)(pw + k0 + 4);
        *(float4*)(p2v)     = *(const float4*)(pb2 + k0);
        *(float4*)(p2v + 4) = *(const float4*)(pb2 + k0 + 4);
#pragma unroll
        for (int i = 0; i < 8; i++) {
            int r = r0 + 16 * i;
            int gn = n0 + r;
            uint4 outv = make_uint4(0, 0, 0, 0);
            if (gn < N) {
                uint4 v = *(const uint4*)(A + (size_t)gn * 128 + k0);
                unsigned uu[4] = {v.x, v.y, v.z, v.w};
                unsigned ro[4];
#pragma unroll
                for (int q2 = 0; q2 < 4; q2++) {
                    float lo = __uint_as_float(uu[q2] << 16);
                    float hi = __uint_as_float(uu[q2] & 0xffff0000u);
                    float t;
                    t = lo + pbv[2 * q2];     t = (t > 0.f) ? t : expm1f(t); lo = t * pwv[2 * q2]     + p2v[2 * q2];
                    t = hi + pbv[2 * q2 + 1]; t = (t > 0.f) ? t : expm1f(t); hi = t * pwv[2 * q2 + 1] + p2v[2 * q2 + 1];
                    ro[q2] = pack_bf16(lo, hi);
                }
                outv = make_uint4(ro[0], ro[1], ro[2], ro[3]);
            }
            *(uint4*)(sA + r * 136 + k0) = outv;
        }
    }
    __syncthreads();

    const int wid = tid >> 6, lane = tid & 63;
    const int quad = lane >> 4, l16 = lane & 15;

    floatx4 acc[2][NCT];
#pragma unroll
    for (int rt = 0; rt < 2; rt++)
#pragma unroll
        for (int ct = 0; ct < NCT; ct++) acc[rt][ct] = (floatx4){0.f, 0.f, 0.f, 0.f};

    const unsigned short* pa0 = sA + (wid * 32 + l16) * 136 + quad * 8;
    const unsigned short* pbt = sB + l16 * 136 + quad * 8;
#pragma unroll
    for (int ks = 0; ks < 4; ks++) {
        short8v a0 = *(const short8v*)(pa0 + ks * 32);
        short8v a1 = *(const short8v*)(pa0 + 16 * 136 + ks * 32);
#pragma unroll
        for (int ct = 0; ct < NCT; ct++) {
            short8v bv = *(const short8v*)(pbt + ct * (16 * 136) + ks * 32);
            acc[0][ct] = __builtin_amdgcn_mfma_f32_16x16x32_bf16(a0, bv, acc[0][ct], 0, 0, 0);
            acc[1][ct] = __builtin_amdgcn_mfma_f32_16x16x32_bf16(a1, bv, acc[1][ct], 0, 0, 0);
        }
    }

    // epilogue: lane = rows quad*4+r, col ct*16+l16
#pragma unroll
    for (int rt = 0; rt < 2; rt++) {
#pragma unroll
        for (int r = 0; r < 4; r++) {
            int n = n0 + wid * 32 + rt * 16 + quad * 4 + r;
            if (n >= N) continue;
            float s = MODE ? dinv[n] : 1.f;
#pragma unroll
            for (int ct = 0; ct < 4; ct++) {
                Cb[(size_t)n * 64 + ct * 16 + l16] =
                    pack_bf16(acc[rt][ct][r] * s, acc[rt][ct + 4][r] * s);
            }
            if (MODE == 0) {
                float e = acc[rt][8][r];
                if (l16 < 4) aS[(size_t)n * 4 + l16] = e;
                else if (l16 < 8) aD[(size_t)n * 4 + (l16 - 4)] = e;
            }
        }
    }
}

// ---------------- GAT aggregation: 2 nodes/wave, 16 nodes/block ------------
// hb pair t = channels (t, t+64); lane l owns (l, l+64); hA = l>>5.
// Two independent per-node chains per wave; combined gather stream through a
// 4-buffer static software pipeline (~32 loads outstanding).
__global__ __launch_bounds__(512, 4) void k_gat_aggr(
    const unsigned* __restrict__ hb, const float* __restrict__ aSg,
    const float* __restrict__ aDg, const int* __restrict__ offs,
    const int* __restrict__ deg, const int* __restrict__ csr,
    unsigned short* __restrict__ raw1b, int N)
{
    __shared__ __align__(16) float s_u[8][2][2][64][2]; // [wid][node][hA][e][pair]
    __shared__ __align__(16) int s_s[8][2][64];

    const int wid = threadIdx.x >> 6;
    const int lane = threadIdx.x & 63;
    const int nA = blockIdx.x * 16 + wid * 2;
    if (nA >= N) return;
    const int nB = nA + 1;
    const bool hasB = nB < N;

    const int begA = offs[nA];
    const int cntA = deg[nA] + 1;                   // + self loop
    const int begB = hasB ? offs[nB] : 0;
    const int cntB = hasB ? deg[nB] + 1 : 0;
    const float4 adA = *(const float4*)(aDg + (size_t)nA * 4);
    const float4 adB = hasB ? *(const float4*)(aDg + (size_t)nB * 4)
                            : make_float4(0.f, 0.f, 0.f, 0.f);
    const int hA_ = lane >> 5;
    const float* puA = &s_u[wid][0][hA_][0][0];
    const float* puB = &s_u[wid][1][hA_][0][0];
    const int* psA = &s_s[wid][0][0];
    const int* psB = &s_s[wid][1][0];
    const unsigned* hbl = hb + lane;

    float tA0 = 0.f, tA1 = 0.f, tA2 = 0.f, tA3 = 0.f;
    float tB0 = 0.f, tB1 = 0.f, tB2 = 0.f, tB3 = 0.f;
    float accLoA = 0.f, accHiA = 0.f, accLoB = 0.f, accHiB = 0.f;

    auto issue8 = [&](const int* ps, int j, unsigned (&v)[8]) {
        int4 A = *(const int4*)&ps[j];
        int4 B = *(const int4*)&ps[j + 4];
        int s0 = __builtin_amdgcn_readfirstlane(A.x);
        int s1 = __builtin_amdgcn_readfirstlane(A.y);
        int s2 = __builtin_amdgcn_readfirstlane(A.z);
        int s3 = __builtin_amdgcn_readfirstlane(A.w);
        int s4 = __builtin_amdgcn_readfirstlane(B.x);
        int s5 = __builtin_amdgcn_readfirstlane(B.y);
        int s6 = __builtin_amdgcn_readfirstlane(B.z);
        int s7 = __builtin_amdgcn_readfirstlane(B.w);
        v[0] = hbl[(size_t)s0 << 6];
        v[1] = hbl[(size_t)s1 << 6];
        v[2] = hbl[(size_t)s2 << 6];
        v[3] = hbl[(size_t)s3 << 6];
        v[4] = hbl[(size_t)s4 << 6];
        v[5] = hbl[(size_t)s5 << 6];
        v[6] = hbl[(size_t)s6 << 6];
        v[7] = hbl[(size_t)s7 << 6];
    };
    auto consume8 = [&](const float* pu, int j, unsigned (&v)[8],
                        float& aLo, float& aHi) {
        float4 u01 = *(const float4*)&pu[2 * j];
        float4 u23 = *(const float4*)&pu[2 * j + 4];
        float4 u45 = *(const float4*)&pu[2 * j + 8];
        float4 u67 = *(const float4*)&pu[2 * j + 12];
        float uw[16] = {u01.x, u01.y, u01.z, u01.w,
                        u23.x, u23.y, u23.z, u23.w,
                        u45.x, u45.y, u45.z, u45.w,
                        u67.x, u67.y, u67.z, u67.w};
#pragma unroll
        for (int k = 0; k < 8; k++) {
            float lo = __uint_as_float(v[k] << 16);
            float hi = __uint_as_float(v[k] & 0xffff0000u);
            aLo += uw[2 * k] * lo;
            aHi += uw[2 * k + 1] * hi;
        }
    };

    const int cntM = cntA > cntB ? cntA : cntB;
    for (int base = 0; base < cntM; base += 64) {
        const bool actA = base < cntA, actB = base < cntB;
        // ---- stage node A ----
        if (actA) {
            int idx = base + lane;
            bool valid = idx < cntA;
            int src = nA;
            if (valid && idx > 0) src = csr[begA + idx - 1];
            float u0 = 0.f, u1 = 0.f, u2 = 0.f, u3 = 0.f;
            if (valid) {
                float4 as = *(const float4*)(aSg + (size_t)src * 4);
                float l0 = as.x + adA.x; l0 = (l0 > 0.f) ? l0 : NEG_SLOPE * l0;
                float l1 = as.y + adA.y; l1 = (l1 > 0.f) ? l1 : NEG_SLOPE * l1;
                float l2 = as.z + adA.z; l2 = (l2 > 0.f) ? l2 : NEG_SLOPE * l2;
                float l3 = as.w + adA.w; l3 = (l3 > 0.f) ? l3 : NEG_SLOPE * l3;
                u0 = __expf(l0); u1 = __expf(l1); u2 = __expf(l2); u3 = __expf(l3);
            }
            tA0 += u0; tA1 += u1; tA2 += u2; tA3 += u3;
            s_s[wid][0][lane] = src;
            *(float2*)&s_u[wid][0][0][lane][0] = make_float2(u0, u2);
            *(float2*)&s_u[wid][0][1][lane][0] = make_float2(u1, u3);
        }
        // ---- stage node B ----
        if (actB) {
            int idx = base + lane;
            bool valid = idx < cntB;
            int src = nB;
            if (valid && idx > 0) src = csr[begB + idx - 1];
            float u0 = 0.f, u1 = 0.f, u2 = 0.f, u3 = 0.f;
            if (valid) {
                float4 as = *(const float4*)(aSg + (size_t)src * 4);
                float l0 = as.x + adB.x; l0 = (l0 > 0.f) ? l0 : NEG_SLOPE * l0;
                float l1 = as.y + adB.y; l1 = (l1 > 0.f) ? l1 : NEG_SLOPE * l1;
                float l2 = as.z + adB.z; l2 = (l2 > 0.f) ? l2 : NEG_SLOPE * l2;
                float l3 = as.w + adB.w; l3 = (l3 > 0.f) ? l3 : NEG_SLOPE * l3;
                u0 = __expf(l0); u1 = __expf(l1); u2 = __expf(l2); u3 = __expf(l3);
            }
            tB0 += u0; tB1 += u1; tB2 += u2; tB3 += u3;
            s_s[wid][1][lane] = src;
            *(float2*)&s_u[wid][1][0][lane][0] = make_float2(u0, u2);
            *(float2*)&s_u[wid][1][1][lane][0] = make_float2(u1, u3);
        }

        const int ngA = actA ? (((min(64, cntA - base)) + 7) & ~7) >> 3 : 0;
        const int ngB = actB ? (((min(64, cntB - base)) + 7) & ~7) >> 3 : 0;
        const int ng = ngA + ngB;

        auto issueI = [&](int i, unsigned (&v)[8]) {
            if (i < ngA) issue8(psA, 8 * i, v);
            else issue8(psB, 8 * (i - ngA), v);
        };
        auto consumeI = [&](int i, unsigned (&v)[8]) {
            if (i < ngA) consume8(puA, 8 * i, v, accLoA, accHiA);
            else consume8(puB, 8 * (i - ngA), v, accLoB, accHiB);
        };

        unsigned v0[8], v1[8], v2[8], v3[8];
        if (ng > 0) issueI(0, v0);
        if (ng > 1) issueI(1, v1);
        if (ng > 2) issueI(2, v2);
        if (ng > 3) issueI(3, v3);
        for (int i = 0; i < ng; i += 4) {
            consumeI(i, v0);
            if (i + 4 < ng) issueI(i + 4, v0);
            if (i + 1 < ng) { consumeI(i + 1, v1); if (i + 5 < ng) issueI(i + 5, v1); }
            if (i + 2 < ng) { consumeI(i + 2, v2); if (i + 6 < ng) issueI(i + 6, v2); }
            if (i + 3 < ng) { consumeI(i + 3, v3); if (i + 7 < ng) issueI(i + 7, v3); }
        }
    }
#pragma unroll
    for (int msk = 1; msk < 64; msk <<= 1) {
        tA0 += __shfl_xor(tA0, msk);
        tA1 += __shfl_xor(tA1, msk);
        tA2 += __shfl_xor(tA2, msk);
        tA3 += __shfl_xor(tA3, msk);
        tB0 += __shfl_xor(tB0, msk);
        tB1 += __shfl_xor(tB1, msk);
        tB2 += __shfl_xor(tB2, msk);
        tB3 += __shfl_xor(tB3, msk);
    }
    float sLoA = (hA_ ? tA1 : tA0) + 1e-16f;
    float sHiA = (hA_ ? tA3 : tA2) + 1e-16f;
    raw1b[(size_t)nA * 128 + lane]      = bf16_1(accLoA / sLoA);
    raw1b[(size_t)nA * 128 + 64 + lane] = bf16_1(accHiA / sHiA);
    if (hasB) {
        float sLoB = (hA_ ? tB1 : tB0) + 1e-16f;
        float sHiB = (hA_ ? tB3 : tB2) + 1e-16f;
        raw1b[(size_t)nB * 128 + lane]      = bf16_1(accLoB / sLoB);
        raw1b[(size_t)nB * 128 + 64 + lane] = bf16_1(accHiB / sHiB);
    }
}

// ---------------- GCN aggregation + fused BN2/ELU/gate/fc ------------------
// Same 2-nodes/wave structure; explicit 1/0 edge weight covers the pads.
__global__ __launch_bounds__(512, 4) void k_gcn_aggr(
    const unsigned* __restrict__ h2b, const int* __restrict__ offs,
    const int* __restrict__ deg, const int* __restrict__ csr,
    const float* __restrict__ dinv, const float* __restrict__ bgcn,
    const float* __restrict__ bn2w, const float* __restrict__ bn2b,
    const float* __restrict__ wgate, const float* __restrict__ bgate,
    const float* __restrict__ wfc,
    float* __restrict__ gate, float* __restrict__ fcdot, int N)
{
    __shared__ __align__(16) int s_s[8][2][64];
    __shared__ __align__(16) float s_w[8][2][64];

    const int wid = threadIdx.x >> 6;
    const int lane = threadIdx.x & 63;
    const int nA = blockIdx.x * 16 + wid * 2;
    if (nA >= N) return;
    const int nB = nA + 1;
    const bool hasB = nB < N;

    const int begA = offs[nA];
    const int cntA = deg[nA] + 1;
    const int begB = hasB ? offs[nB] : 0;
    const int cntB = hasB ? deg[nB] + 1 : 0;
    const int* psA = &s_s[wid][0][0];
    const int* psB = &s_s[wid][1][0];
    const float* pwA = &s_w[wid][0][0];
    const float* pwB = &s_w[wid][1][0];
    const unsigned* h2l = h2b + lane;

    float accLoA = 0.f, accHiA = 0.f, accLoB = 0.f, accHiB = 0.f;

    auto issue8 = [&](const int* ps, int j, unsigned (&v)[8]) {
        int4 A = *(const int4*)&ps[j];
        int4 B = *(const int4*)&ps[j + 4];
        int s0 = __builtin_amdgcn_readfirstlane(A.x);
        int s1 = __builtin_amdgcn_readfirstlane(A.y);
        int s2 = __builtin_amdgcn_readfirstlane(A.z);
        int s3 = __builtin_amdgcn_readfirstlane(A.w);
        int s4 = __builtin_amdgcn_readfirstlane(B.x);
        int s5 = __builtin_amdgcn_readfirstlane(B.y);
        int s6 = __builtin_amdgcn_readfirstlane(B.z);
        int s7 = __builtin_amdgcn_readfirstlane(B.w);
        v[0] = h2l[(size_t)s0 << 6];
        v[1] = h2l[(size_t)s1 << 6];
        v[2] = h2l[(size_t)s2 << 6];
        v[3] = h2l[(size_t)s3 << 6];
        v[4] = h2l[(size_t)s4 << 6];
        v[5] = h2l[(size_t)s5 << 6];
        v[6] = h2l[(size_t)s6 << 6];
        v[7] = h2l[(size_t)s7 << 6];
    };
    auto consume8 = [&](const float* pw, int j, unsigned (&v)[8],
                        float& aLo, float& aHi) {
        float4 wA = *(const float4*)&pw[j];
        float4 wB = *(const float4*)&pw[j + 4];
        float w8[8] = {wA.x, wA.y, wA.z, wA.w, wB.x, wB.y, wB.z, wB.w};
#pragma unroll
        for (int k = 0; k < 8; k++) {
            float lo = __uint_as_float(v[k] << 16);
            float hi = __uint_as_float(v[k] & 0xffff0000u);
            aLo += w8[k] * lo;
            aHi += w8[k] * hi;
        }
    };

    const int cntM = cntA > cntB ? cntA : cntB;
    for (int base = 0; base < cntM; base += 64) {
        const bool actA = base < cntA, actB = base < cntB;
        if (actA) {
            int idx = base + lane;
            bool valid = idx < cntA;
            int src = nA;
            if (valid && idx > 0) src = csr[begA + idx - 1];
            s_s[wid][0][lane] = src;
            s_w[wid][0][lane] = valid ? 1.f : 0.f;
        }
        if (actB) {
            int idx = base + lane;
            bool valid = idx < cntB;
            int src = nB;
            if (valid && idx > 0) src = csr[begB + idx - 1];
            s_s[wid][1][lane] = src;
            s_w[wid][1][lane] = valid ? 1.f : 0.f;
        }

        const int ngA = actA ? (((min(64, cntA - base)) + 7) & ~7) >> 3 : 0;
        const int ngB = actB ? (((min(64, cntB - base)) + 7) & ~7) >> 3 : 0;
        const int ng = ngA + ngB;

        auto issueI = [&](int i, unsigned (&v)[8]) {
            if (i < ngA) issue8(psA, 8 * i, v);
            else issue8(psB, 8 * (i - ngA), v);
        };
        auto consumeI = [&](int i, unsigned (&v)[8]) {
            if (i < ngA) consume8(pwA, 8 * i, v, accLoA, accHiA);
            else consume8(pwB, 8 * (i - ngA), v, accLoB, accHiB);
        };

        unsigned v0[8], v1[8], v2[8], v3[8];
        if (ng > 0) issueI(0, v0);
        if (ng > 1) issueI(1, v1);
        if (ng > 2) issueI(2, v2);
        if (ng > 3) issueI(3, v3);
        for (int i = 0; i < ng; i += 4) {
            consumeI(i, v0);
            if (i + 4 < ng) issueI(i + 4, v0);
            if (i + 1 < ng) { consumeI(i + 1, v1); if (i + 5 < ng) issueI(i + 5, v1); }
            if (i + 2 < ng) { consumeI(i + 2, v2); if (i + 6 < ng) issueI(i + 6, v2); }
            if (i + 3 < ng) { consumeI(i + 3, v3); if (i + 7 < ng) issueI(i + 7, v3); }
        }
    }

    auto epilogue = [&](int n, float accLo, float accHi) {
        float dn = dinv[n];
        float v0f = dn * accLo + bgcn[lane];
        v0f = (v0f > 0.f) ? v0f : expm1f(v0f);
        v0f = v0f * bn2w[lane] + bn2b[lane];
        float v1f = dn * accHi + bgcn[lane + 64];
        v1f = (v1f > 0.f) ? v1f : expm1f(v1f);
        v1f = v1f * bn2w[lane + 64] + bn2b[lane + 64];
        float g = v0f * wgate[lane] + v1f * wgate[lane + 64];
        float f = v0f * wfc[lane]   + v1f * wfc[lane + 64];
#pragma unroll
        for (int msk = 1; msk < 64; msk <<= 1) {
            g += __shfl_xor(g, msk);
            f += __shfl_xor(f, msk);
        }
        if (lane == 0) { gate[n] = g + bgate[0]; fcdot[n] = f; }
    };
    epilogue(nA, accLoA, accHiA);
    if (hasB) epilogue(nB, accLoB, accHiB);
}

// ---------------- pooling softmax over scalars: one block / graph ----------
__global__ __launch_bounds__(256) void k_pool(
    const float* __restrict__ gate, const float* __restrict__ fcdot,
    const int* __restrict__ batch, const float* __restrict__ bfc,
    float* __restrict__ out, int N)
{
    __shared__ float red[256];
    __shared__ int range[2];
    const int g = blockIdx.x;
    const int tid = threadIdx.x;
    if (tid < 2) range[tid] = lower_bound_i(batch, N, g + tid);
    __syncthreads();
    const int lo = range[0], hi = range[1];
    float se = 0.f, sf = 0.f;
    for (int i = lo + tid; i < hi; i += 256) {
        float e = __expf(gate[i]);
        se += e;
        sf += e * fcdot[i];
    }
    red[tid] = se; __syncthreads();
    for (int s = 128; s > 0; s >>= 1) {
        if (tid < s) red[tid] += red[tid + s];
        __syncthreads();
    }
    se = red[0]; __syncthreads();
    red[tid] = sf; __syncthreads();
    for (int s = 128; s > 0; s >>= 1) {
        if (tid < s) red[tid] += red[tid + s];
        __syncthreads();
    }
    sf = red[0];
    if (tid == 0) out[g] = sf / (se + 1e-16f) + bfc[0];
}

// ---------------------------------------------------------------------------
extern "C" void kernel_launch(void* const* d_in, const int* in_sizes, int n_in,
                              void* d_out, int out_size, void* d_ws, size_t ws_size,
                              hipStream_t stream) {
    const float* x     = (const float*)d_in[0];
    const int*   ei    = (const int*)d_in[1];
    const int*   batch = (const int*)d_in[2];
    const float* Wgat  = (const float*)d_in[3];
    const float* atts  = (const float*)d_in[4];
    const float* attd  = (const float*)d_in[5];
    const float* bgat  = (const float*)d_in[6];
    const float* bn1w  = (const float*)d_in[7];
    const float* bn1b  = (const float*)d_in[8];
    const float* Wgcn  = (const float*)d_in[9];
    const float* bgcn  = (const float*)d_in[10];
    const float* bn2w  = (const float*)d_in[11];
    const float* bn2b  = (const float*)d_in[12];
    const float* wgate = (const float*)d_in[13];
    const float* bgate = (const float*)d_in[14];
    const float* wfc   = (const float*)d_in[15];
    const float* bfc   = (const float*)d_in[16];
    float* out = (float*)d_out;

    const int N = in_sizes[0] / 128;
    const int E = in_sizes[1] / 2;
    const int NB = (N + BKT_SIZE - 1) / BKT_SIZE;
    const int NBA = (E + CHUNK_A - 1) / CHUNK_A;   // binA blocks

    unsigned* hb  = (unsigned*)d_ws;               // bf16 h table   [N*64]
    unsigned* h2b = hb + (size_t)N * 64;           // bf16 h2s table [N*64]
    unsigned short* raw1b = (unsigned short*)(h2b + (size_t)N * 64); // [N*128]
    float* aS    = (float*)(raw1b + (size_t)N * 128); // [N*4]
    float* aD    = aS + (size_t)N * 4;             // [N*4]
    float* gate  = aD + (size_t)N * 4;             // [N]
    float* fcdot = gate + N;                       // [N]
    float* dinv  = fcdot + N;                      // [N]
    int* offs   = (int*)(dinv + N);                // [N]
    int* deg    = offs + N;                        // [N]
    int* bcur   = deg + N;                         // [NB+1]
    unsigned short* Wt1 = (unsigned short*)(bcur + (NB + 1)); // [144*128]
    unsigned short* Wt2 = Wt1 + 144 * 128;                    // [128*128]
    int2* pairs = (int2*)(Wt2 + 128 * 128);        // [(NB+1)*BCAP]
    int* csr    = (int*)(pairs + (size_t)(NB + 1) * BCAP);    // [NB*BCAP]

    hipMemsetAsync(bcur, 0, (size_t)(NB + 1) * sizeof(int), stream);

    const int gemm_blocks = (N + 127) / 128;
    const int aggr_blocks = (N + 15) / 16;

    // L1: weight prep (2 blocks) || edge binning (NBA blocks)
    k_prep<<<NBA + 2, 256, 0, stream>>>(Wgat, atts, attd, Wgcn, Wt1, Wt2,
                                        ei, bcur, pairs, E, NB);
    // L2: gemm0 || binB (padded CSR build) in one launch
    k_gemm_mfma<0><<<gemm_blocks + NB, 256, 0, stream>>>(
        x, Wt1, hb, N, nullptr, nullptr, nullptr, nullptr, aS, aD,
        pairs, bcur, csr, offs, deg, dinv, gemm_blocks);
    // L3..L6
    k_gat_aggr<<<aggr_blocks, 512, 0, stream>>>(hb, aS, aD, offs, deg, csr,
                                                raw1b, N);
    k_gemm_mfma<1><<<gemm_blocks, 256, 0, stream>>>(
        raw1b, Wt2, h2b, N, bgat, bn1w, bn1b, dinv, nullptr, nullptr,
        nullptr, nullptr, nullptr, nullptr, nullptr, nullptr, 1 << 30);
    k_gcn_aggr<<<aggr_blocks, 512, 0, stream>>>(h2b, offs, deg, csr, dinv,
                                                bgcn, bn2w, bn2b, wgate,
                                                bgate, wfc, gate, fcdot, N);
    k_pool<<<64, 256, 0, stream>>>(gate, fcdot, batch, bfc, out, N);
}

// Round 6
// 239.127 us; speedup vs baseline: 1.0956x; 1.0956x over previous
//
#include <hip/hip_runtime.h>
#include <math.h>

// GoBERT: GATConv(4x32) -> BN -> GCNConv(128) -> BN -> GlobalAttention -> FC
// Round 12: revert R11 (2-nodes/wave + branchy pipeline lost 32us: occupancy
// 54->33%, loads serialized by control flow). Back to R10 structure (229.6us)
// with one targeted chain-shortening change in the aggr kernels:
//  - hb/h2b gather indices extracted with v_readlane from the csr values in
//    registers (not via an LDS s_s round trip). The row gathers now issue
//    right after the csr load returns; the aSg gather + exp (gat) overlap
//    them under the same vmcnt window. Serial chain: 3 round trips -> 2.
//  - k_gcn_aggr needs no LDS at all: pad weight = (j+k<cc) uniform predicate.
//  - pads unchanged (src=n, u/w=0) -> accumulation bit-identical to R10.
// prep/gemm/binB/pool identical to R10.

#define NEG_SLOPE 0.2f
#define BKT_BITS 7
#define BKT_SIZE 128
#define CHUNK_A 2048
#define BCAP 4096

typedef __attribute__((ext_vector_type(8))) short short8v;
typedef __attribute__((ext_vector_type(4))) float floatx4;

__device__ __forceinline__ int lower_bound_i(const int* a, int n, int key) {
    int lo = 0, hi = n;
    while (lo < hi) {
        int mid = (lo + hi) >> 1;
        if (a[mid] < key) lo = mid + 1; else hi = mid;
    }
    return lo;
}

__device__ __forceinline__ unsigned pack_bf16(float lo, float hi) {
    unsigned ua = __float_as_uint(lo);
    unsigned ub = __float_as_uint(hi);
    ua = ua + 0x7fffu + ((ua >> 16) & 1u);
    ub = ub + 0x7fffu + ((ub >> 16) & 1u);
    return (ua >> 16) | (ub & 0xffff0000u);
}

__device__ __forceinline__ unsigned short bf16_1(float v) {
    unsigned u = __float_as_uint(v);
    u = u + 0x7fffu + ((u >> 16) & 1u);
    return (unsigned short)(u >> 16);
}

// ---------------- prep: weight transpose (blocks 0-1) || binA (rest) -------
__global__ __launch_bounds__(256) void k_prep(
    const float* __restrict__ W1, const float* __restrict__ atts,
    const float* __restrict__ attd, const float* __restrict__ W2,
    unsigned short* __restrict__ Wt1, unsigned short* __restrict__ Wt2,
    const int* __restrict__ ei, int* __restrict__ bcur,
    int2* __restrict__ pairs, int E, int NB)
{
    __shared__ float sW[128 * 129];          // 64.5KB; aliased by binA branch
    const int b = blockIdx.x;
    const int tid = threadIdx.x;
    if (b < 2) {
        const float* W = b ? W2 : W1;
        unsigned short* Wt = b ? Wt2 : Wt1;
        for (int t = tid; t < 128 * 128; t += 256)
            sW[(t >> 7) * 129 + (t & 127)] = W[t];   // coalesced global read
        __syncthreads();
        const int lim = b ? (128 * 128) : (144 * 128);
        for (int idx = tid; idx < lim; idx += 256) {
            int j = idx >> 7, i = idx & 127;
            float v;
            if (j < 128) v = sW[i * 129 + j];        // lanes vary i: no conflict
            else if (j < 132) {
                int h = j - 128; float s = 0.f;
                for (int c = 0; c < 32; c++) s += sW[i * 129 + h * 32 + c] * atts[h * 32 + c];
                v = s;
            } else if (j < 136) {
                int h = j - 132; float s = 0.f;
                for (int c = 0; c < 32; c++) s += sW[i * 129 + h * 32 + c] * attd[h * 32 + c];
                v = s;
            } else v = 0.f;
            Wt[idx] = bf16_1(v);
        }
    } else {
        int* h    = (int*)sW;                // [512]
        int* base = h + 512;                 // [512]
        for (int i = tid; i < NB + 1; i += 256) h[i] = 0;
        __syncthreads();
        const int c0 = (b - 2) * CHUNK_A;
        int s[8], d[8], bk[8];
#pragma unroll
        for (int k = 0; k < 8; k++) {
            int e = c0 + k * 256 + tid;
            bool v = e < E;
            s[k] = v ? ei[e] : 0;
            d[k] = v ? ei[E + e] : 0;
            bk[k] = v ? (d[k] >> BKT_BITS) : NB;
            atomicAdd(&h[bk[k]], 1);
        }
        __syncthreads();
        for (int i = tid; i < NB + 1; i += 256) {
            int c = h[i];
            base[i] = c ? atomicAdd(&bcur[i], c) : 0;
            h[i] = 0;
        }
        __syncthreads();
#pragma unroll
        for (int k = 0; k < 8; k++) {
            int r = atomicAdd(&h[bk[k]], 1);
            pairs[(size_t)bk[k] * BCAP + base[bk[k]] + r] = make_int2(s[k], d[k]);
        }
    }
}

// ---------------- MFMA GEMM: 128 rows/block, Cb[N,64 pairs] ----------------
// MODE 0 launch also hosts binB in blocks >= gemmBlocks (independent work).
template<int MODE>
__global__ __launch_bounds__(256) void k_gemm_mfma(
    const void* __restrict__ Ain, const unsigned short* __restrict__ Wt,
    unsigned* __restrict__ Cb, int N,
    const float* __restrict__ pb, const float* __restrict__ pw,
    const float* __restrict__ pb2, const float* __restrict__ dinv,
    float* __restrict__ aS, float* __restrict__ aD,
    const int2* __restrict__ pairs, const int* __restrict__ bcnt,
    int* __restrict__ csr, int* __restrict__ offs, int* __restrict__ deg,
    float* __restrict__ dinvw, int gemmBlocks)
{
    constexpr int NCT = (MODE == 0) ? 9 : 8;
    __shared__ unsigned short sA[128 * 136];
    __shared__ unsigned short sB[NCT * 16 * 136];
    const int tid = threadIdx.x;

    if (MODE == 0 && (int)blockIdx.x >= gemmBlocks) {
        // ---------------- binB: bucket -> padded CSR ----------------
        __shared__ int wtot;
        int* hist  = (int*)sA;               // [128]
        int* start = hist + 128;             // [128]
        int* cur   = start + 128;            // [128]
        const int b = blockIdx.x - gemmBlocks;
        const int lane = tid & 63;
        const int d0 = b << BKT_BITS;
        const size_t pbg = (size_t)b * BCAP;
        const int cntb = bcnt[b];
        if (tid < BKT_SIZE) { hist[tid] = 0; cur[tid] = 0; }
        __syncthreads();
        for (int i = tid; i < cntb; i += 256)
            atomicAdd(&hist[pairs[pbg + i].y - d0], 1);
        __syncthreads();
        int own = (tid < BKT_SIZE) ? hist[tid] : 0;
        int incl = own;
#pragma unroll
        for (int st = 1; st < 64; st <<= 1) {
            int t = __shfl_up(incl, st);
            if (lane >= st) incl += t;
        }
        if (tid == 63) wtot = incl;          // wave-0 total
        __syncthreads();
        if (tid < BKT_SIZE) {
            if (tid >= 64) incl += wtot;
            int abs0 = (int)pbg + (incl - own);
            start[tid] = abs0;
            int dd = d0 + tid;
            if (dd < N) {
                offs[dd] = abs0;
                deg[dd] = own;
                dinvw[dd] = rsqrtf((float)(own + 1));
            }
        }
        __syncthreads();
        for (int i = tid; i < cntb; i += 256) {
            int2 p = pairs[pbg + i];
            int ld = p.y - d0;
            int r = atomicAdd(&cur[ld], 1);
            csr[start[ld] + r] = p.x;
        }
        return;
    }

    const int n0 = blockIdx.x * 128;

    // stage B (coalesced uint4, LDS row stride 136)
    {
        const uint4* Wg = (const uint4*)Wt;
        const int nq = NCT * 16 * 16;
        for (int q = tid; q < nq; q += 256) {
            uint4 v = Wg[q];
            int j = q >> 4, seg = q & 15;
            *(uint4*)(sB + j * 136 + seg * 8) = v;
        }
    }
    // stage A
    if (MODE == 0) {
        const float* A = (const float*)Ain;
        const int w4 = tid & 31;          // float4 within row
        const int r0 = tid >> 5;          // 0..7
#pragma unroll
        for (int i = 0; i < 16; i++) {
            int r = r0 + 8 * i;
            int gn = n0 + r;
            unsigned p0 = 0, p1 = 0;
            if (gn < N) {
                float4 v = *(const float4*)(A + (size_t)gn * 128 + w4 * 4);
                p0 = pack_bf16(v.x, v.y);
                p1 = pack_bf16(v.z, v.w);
            }
            *(uint2*)(sA + r * 136 + w4 * 4) = make_uint2(p0, p1);
        }
    } else {
        const unsigned short* A = (const unsigned short*)Ain;
        const int w8 = tid & 15;          // 8-channel group within row
        const int r0 = tid >> 4;          // 0..15
        const int k0 = w8 * 8;
        float pbv[8], pwv[8], p2v[8];
        *(float4*)(pbv)     = *(const float4*)(pb + k0);
        *(float4*)(pbv + 4) = *(const float4*)(pb + k0 + 4);
        *(float4*)(pwv)     = *(const float4*)(pw + k0);
        *(float4*)(pwv + 4) = *(const float4*)(pw + k0 + 4);
        *(float4*)(p2v)     = *(const float4*)(pb2 + k0);
        *(float4*)(p2v + 4) = *(const float4*)(pb2 + k0 + 4);
#pragma unroll
        for (int i = 0; i < 8; i++) {
            int r = r0 + 16 * i;
            int gn = n0 + r;
            uint4 outv = make_uint4(0, 0, 0, 0);
            if (gn < N) {
                uint4 v = *(const uint4*)(A + (size_t)gn * 128 + k0);
                unsigned uu[4] = {v.x, v.y, v.z, v.w};
                unsigned ro[4];
#pragma unroll
                for (int q2 = 0; q2 < 4; q2++) {
                    float lo = __uint_as_float(uu[q2] << 16);
                    float hi = __uint_as_float(uu[q2] & 0xffff0000u);
                    float t;
                    t = lo + pbv[2 * q2];     t = (t > 0.f) ? t : expm1f(t); lo = t * pwv[2 * q2]     + p2v[2 * q2];
                    t = hi + pbv[2 * q2 + 1]; t = (t > 0.f) ? t : expm1f(t); hi = t * pwv[2 * q2 + 1] + p2v[2 * q2 + 1];
                    ro[q2] = pack_bf16(lo, hi);
                }
                outv = make_uint4(ro[0], ro[1], ro[2], ro[3]);
            }
            *(uint4*)(sA + r * 136 + k0) = outv;
        }
    }
    __syncthreads();

    const int wid = tid >> 6, lane = tid & 63;
    const int quad = lane >> 4, l16 = lane & 15;

    floatx4 acc[2][NCT];
#pragma unroll
    for (int rt = 0; rt < 2; rt++)
#pragma unroll
        for (int ct = 0; ct < NCT; ct++) acc[rt][ct] = (floatx4){0.f, 0.f, 0.f, 0.f};

    const unsigned short* pa0 = sA + (wid * 32 + l16) * 136 + quad * 8;
    const unsigned short* pbt = sB + l16 * 136 + quad * 8;
#pragma unroll
    for (int ks = 0; ks < 4; ks++) {
        short8v a0 = *(const short8v*)(pa0 + ks * 32);
        short8v a1 = *(const short8v*)(pa0 + 16 * 136 + ks * 32);
#pragma unroll
        for (int ct = 0; ct < NCT; ct++) {
            short8v bv = *(const short8v*)(pbt + ct * (16 * 136) + ks * 32);
            acc[0][ct] = __builtin_amdgcn_mfma_f32_16x16x32_bf16(a0, bv, acc[0][ct], 0, 0, 0);
            acc[1][ct] = __builtin_amdgcn_mfma_f32_16x16x32_bf16(a1, bv, acc[1][ct], 0, 0, 0);
        }
    }

    // epilogue: lane = rows quad*4+r, col ct*16+l16
#pragma unroll
    for (int rt = 0; rt < 2; rt++) {
#pragma unroll
        for (int r = 0; r < 4; r++) {
            int n = n0 + wid * 32 + rt * 16 + quad * 4 + r;
            if (n >= N) continue;
            float s = MODE ? dinv[n] : 1.f;
#pragma unroll
            for (int ct = 0; ct < 4; ct++) {
                Cb[(size_t)n * 64 + ct * 16 + l16] =
                    pack_bf16(acc[rt][ct][r] * s, acc[rt][ct + 4][r] * s);
            }
            if (MODE == 0) {
                float e = acc[rt][8][r];
                if (l16 < 4) aS[(size_t)n * 4 + l16] = e;
                else if (l16 < 8) aD[(size_t)n * 4 + (l16 - 4)] = e;
            }
        }
    }
}

// ---------------- GAT aggregation: 8 nodes / 512-thread block --------------
// hb pair t = channels (t, t+64); lane l owns (l, l+64); hA = l>>5.
// Indices for the row gathers come straight from the csr values in registers
// via v_readlane -> gathers issue one round trip after the csr load; the aSg
// 16B/lane gather + exp overlap them. u weights still staged in LDS (read by
// consume, which runs after the vmcnt wait anyway). Pads: src=n, u=0.
__global__ __launch_bounds__(512, 2) void k_gat_aggr(
    const unsigned* __restrict__ hb, const float* __restrict__ aSg,
    const float* __restrict__ aDg, const int* __restrict__ offs,
    const int* __restrict__ deg, const int* __restrict__ csr,
    unsigned short* __restrict__ raw1b, int N)
{
    __shared__ __align__(16) float s_u[8][2][64][2];   // [wid][hA][edge][pair]

    const int wid = threadIdx.x >> 6;
    const int lane = threadIdx.x & 63;
    const int n = blockIdx.x * 8 + wid;
    if (n >= N) return;

    const int beg = offs[n];
    const int cnt = deg[n] + 1;                     // + self loop
    const float4 ad = *(const float4*)(aDg + (size_t)n * 4);
    const int hA = lane >> 5;
    const float* pu = &s_u[wid][hA][0][0];
    const unsigned* hbl = hb + lane;

    float t0 = 0.f, t1 = 0.f, t2 = 0.f, t3 = 0.f;
    float accLo = 0.f, accHi = 0.f;

    auto issueRL = [&](int srcv, int j, unsigned (&v)[8]) {
#pragma unroll
        for (int k = 0; k < 8; k++) {
            int sa = __builtin_amdgcn_readlane(srcv, j + k);
            v[k] = hbl[(size_t)sa << 6];
        }
    };
    auto consume8 = [&](int j, unsigned (&v)[8]) {
        float4 u01 = *(const float4*)&pu[2 * j];
        float4 u23 = *(const float4*)&pu[2 * j + 4];
        float4 u45 = *(const float4*)&pu[2 * j + 8];
        float4 u67 = *(const float4*)&pu[2 * j + 12];
        float uw[16] = {u01.x, u01.y, u01.z, u01.w,
                        u23.x, u23.y, u23.z, u23.w,
                        u45.x, u45.y, u45.z, u45.w,
                        u67.x, u67.y, u67.z, u67.w};
#pragma unroll
        for (int k = 0; k < 8; k++) {
            float lo = __uint_as_float(v[k] << 16);
            float hi = __uint_as_float(v[k] & 0xffff0000u);
            accLo += uw[2 * k] * lo;
            accHi += uw[2 * k + 1] * hi;
        }
    };

    for (int base = 0; base < cnt; base += 64) {
        int idx = base + lane;
        bool valid = idx < cnt;
        int src = n;
        if (valid && idx > 0) src = csr[beg + idx - 1];

        // issue the row gathers immediately (indices from registers)
        int cc = min(64, cnt - base);
        int ccp = (cc + 7) & ~7;                    // pads contribute u=0
        int ng = ccp >> 3;
        unsigned v0[8], v1[8], v2[8];
        if (ng > 0) issueRL(src, 0, v0);
        if (ng > 1) issueRL(src, 8, v1);
        if (ng > 2) issueRL(src, 16, v2);

        // aSg gather + exp overlap the row gathers
        float u0 = 0.f, u1 = 0.f, u2 = 0.f, u3 = 0.f;
        if (valid) {
            float4 as = *(const float4*)(aSg + (size_t)src * 4);
            float l0 = as.x + ad.x; l0 = (l0 > 0.f) ? l0 : NEG_SLOPE * l0;
            float l1 = as.y + ad.y; l1 = (l1 > 0.f) ? l1 : NEG_SLOPE * l1;
            float l2 = as.z + ad.z; l2 = (l2 > 0.f) ? l2 : NEG_SLOPE * l2;
            float l3 = as.w + ad.w; l3 = (l3 > 0.f) ? l3 : NEG_SLOPE * l3;
            u0 = __expf(l0); u1 = __expf(l1); u2 = __expf(l2); u3 = __expf(l3);
        }
        t0 += u0; t1 += u1; t2 += u2; t3 += u3;
        *(float2*)&s_u[wid][0][lane][0] = make_float2(u0, u2);
        *(float2*)&s_u[wid][1][lane][0] = make_float2(u1, u3);

        if (ng > 0) consume8(0, v0);
        if (ng > 1) consume8(8, v1);
        if (ng > 2) consume8(16, v2);
        for (int j = 24; j < ccp; j += 8) {         // rare (deg > 23)
            issueRL(src, j, v0);
            consume8(j, v0);
        }
    }
#pragma unroll
    for (int msk = 1; msk < 64; msk <<= 1) {
        t0 += __shfl_xor(t0, msk);
        t1 += __shfl_xor(t1, msk);
        t2 += __shfl_xor(t2, msk);
        t3 += __shfl_xor(t3, msk);
    }
    float sLo = (hA ? t1 : t0) + 1e-16f;
    float sHi = (hA ? t3 : t2) + 1e-16f;
    raw1b[(size_t)n * 128 + lane]      = bf16_1(accLo / sLo);
    raw1b[(size_t)n * 128 + 64 + lane] = bf16_1(accHi / sHi);
}

// ---------------- GCN aggregation + fused BN2/ELU/gate/fc ------------------
// readlane indices; pad weight is the uniform predicate (j+k < cc); no LDS.
__global__ __launch_bounds__(512, 2) void k_gcn_aggr(
    const unsigned* __restrict__ h2b, const int* __restrict__ offs,
    const int* __restrict__ deg, const int* __restrict__ csr,
    const float* __restrict__ dinv, const float* __restrict__ bgcn,
    const float* __restrict__ bn2w, const float* __restrict__ bn2b,
    const float* __restrict__ wgate, const float* __restrict__ bgate,
    const float* __restrict__ wfc,
    float* __restrict__ gate, float* __restrict__ fcdot, int N)
{
    const int wid = threadIdx.x >> 6;
    const int lane = threadIdx.x & 63;
    const int n = blockIdx.x * 8 + wid;
    if (n >= N) return;

    const int beg = offs[n];
    const int cnt = deg[n] + 1;
    const float dn = dinv[n];
    const unsigned* h2l = h2b + lane;

    float accLo = 0.f, accHi = 0.f;

    auto issueRL = [&](int srcv, int j, unsigned (&v)[8]) {
#pragma unroll
        for (int k = 0; k < 8; k++) {
            int sa = __builtin_amdgcn_readlane(srcv, j + k);
            v[k] = h2l[(size_t)sa << 6];
        }
    };
    auto consume8 = [&](int j, int cc, unsigned (&v)[8]) {
#pragma unroll
        for (int k = 0; k < 8; k++) {
            if (j + k < cc) {                       // wave-uniform predicate
                accLo += __uint_as_float(v[k] << 16);
                accHi += __uint_as_float(v[k] & 0xffff0000u);
            }
        }
    };

    for (int base = 0; base < cnt; base += 64) {
        int idx = base + lane;
        int src = n;
        if (idx > 0 && idx < cnt) src = csr[beg + idx - 1];

        int cc = min(64, cnt - base);
        int ccp = (cc + 7) & ~7;
        int ng = ccp >> 3;
        unsigned v0[8], v1[8], v2[8];
        if (ng > 0) issueRL(src, 0, v0);
        if (ng > 1) issueRL(src, 8, v1);
        if (ng > 2) issueRL(src, 16, v2);
        if (ng > 0) consume8(0, cc, v0);
        if (ng > 1) consume8(8, cc, v1);
        if (ng > 2) consume8(16, cc, v2);
        for (int j = 24; j < ccp; j += 8) {
            issueRL(src, j, v0);
            consume8(j, cc, v0);
        }
    }
    float v0f = dn * accLo + bgcn[lane];
    v0f = (v0f > 0.f) ? v0f : expm1f(v0f);
    v0f = v0f * bn2w[lane] + bn2b[lane];
    float v1f = dn * accHi + bgcn[lane + 64];
    v1f = (v1f > 0.f) ? v1f : expm1f(v1f);
    v1f = v1f * bn2w[lane + 64] + bn2b[lane + 64];

    float g = v0f * wgate[lane] + v1f * wgate[lane + 64];
    float f = v0f * wfc[lane]   + v1f * wfc[lane + 64];
#pragma unroll
    for (int msk = 1; msk < 64; msk <<= 1) {
        g += __shfl_xor(g, msk);
        f += __shfl_xor(f, msk);
    }
    if (lane == 0) { gate[n] = g + bgate[0]; fcdot[n] = f; }
}

// ---------------- pooling softmax over scalars: one block / graph ----------
__global__ __launch_bounds__(256) void k_pool(
    const float* __restrict__ gate, const float* __restrict__ fcdot,
    const int* __restrict__ batch, const float* __restrict__ bfc,
    float* __restrict__ out, int N)
{
    __shared__ float red[256];
    __shared__ int range[2];
    const int g = blockIdx.x;
    const int tid = threadIdx.x;
    if (tid < 2) range[tid] = lower_bound_i(batch, N, g + tid);
    __syncthreads();
    const int lo = range[0], hi = range[1];
    float se = 0.f, sf = 0.f;
    for (int i = lo + tid; i < hi; i += 256) {
        float e = __expf(gate[i]);
        se += e;
        sf += e * fcdot[i];
    }
    red[tid] = se; __syncthreads();
    for (int s = 128; s > 0; s >>= 1) {
        if (tid < s) red[tid] += red[tid + s];
        __syncthreads();
    }
    se = red[0]; __syncthreads();
    red[tid] = sf; __syncthreads();
    for (int s = 128; s > 0; s >>= 1) {
        if (tid < s) red[tid] += red[tid + s];
        __syncthreads();
    }
    sf = red[0];
    if (tid == 0) out[g] = sf / (se + 1e-16f) + bfc[0];
}

// ---------------------------------------------------------------------------
extern "C" void kernel_launch(void* const* d_in, const int* in_sizes, int n_in,
                              void* d_out, int out_size, void* d_ws, size_t ws_size,
                              hipStream_t stream) {
    const float* x     = (const float*)d_in[0];
    const int*   ei    = (const int*)d_in[1];
    const int*   batch = (const int*)d_in[2];
    const float* Wgat  = (const float*)d_in[3];
    const float* atts  = (const float*)d_in[4];
    const float* attd  = (const float*)d_in[5];
    const float* bgat  = (const float*)d_in[6];
    const float* bn1w  = (const float*)d_in[7];
    const float* bn1b  = (const float*)d_in[8];
    const float* Wgcn  = (const float*)d_in[9];
    const float* bgcn  = (const float*)d_in[10];
    const float* bn2w  = (const float*)d_in[11];
    const float* bn2b  = (const float*)d_in[12];
    const float* wgate = (const float*)d_in[13];
    const float* bgate = (const float*)d_in[14];
    const float* wfc   = (const float*)d_in[15];
    const float* bfc   = (const float*)d_in[16];
    float* out = (float*)d_out;

    const int N = in_sizes[0] / 128;
    const int E = in_sizes[1] / 2;
    const int NB = (N + BKT_SIZE - 1) / BKT_SIZE;
    const int NBA = (E + CHUNK_A - 1) / CHUNK_A;   // binA blocks

    unsigned* hb  = (unsigned*)d_ws;               // bf16 h table   [N*64]
    unsigned* h2b = hb + (size_t)N * 64;           // bf16 h2s table [N*64]
    unsigned short* raw1b = (unsigned short*)(h2b + (size_t)N * 64); // [N*128]
    float* aS    = (float*)(raw1b + (size_t)N * 128); // [N*4]
    float* aD    = aS + (size_t)N * 4;             // [N*4]
    float* gate  = aD + (size_t)N * 4;             // [N]
    float* fcdot = gate + N;                       // [N]
    float* dinv  = fcdot + N;                      // [N]
    int* offs   = (int*)(dinv + N);                // [N]
    int* deg    = offs + N;                        // [N]
    int* bcur   = deg + N;                         // [NB+1]
    unsigned short* Wt1 = (unsigned short*)(bcur + (NB + 1)); // [144*128]
    unsigned short* Wt2 = Wt1 + 144 * 128;                    // [128*128]
    int2* pairs = (int2*)(Wt2 + 128 * 128);        // [(NB+1)*BCAP]
    int* csr    = (int*)(pairs + (size_t)(NB + 1) * BCAP);    // [NB*BCAP]

    hipMemsetAsync(bcur, 0, (size_t)(NB + 1) * sizeof(int), stream);

    const int gemm_blocks = (N + 127) / 128;
    const int aggr_blocks = (N + 7) / 8;

    // L1: weight prep (2 blocks) || edge binning (NBA blocks)
    k_prep<<<NBA + 2, 256, 0, stream>>>(Wgat, atts, attd, Wgcn, Wt1, Wt2,
                                        ei, bcur, pairs, E, NB);
    // L2: gemm0 || binB (padded CSR build) in one launch
    k_gemm_mfma<0><<<gemm_blocks + NB, 256, 0, stream>>>(
        x, Wt1, hb, N, nullptr, nullptr, nullptr, nullptr, aS, aD,
        pairs, bcur, csr, offs, deg, dinv, gemm_blocks);
    // L3..L6
    k_gat_aggr<<<aggr_blocks, 512, 0, stream>>>(hb, aS, aD, offs, deg, csr,
                                                raw1b, N);
    k_gemm_mfma<1><<<gemm_blocks, 256, 0, stream>>>(
        raw1b, Wt2, h2b, N, bgat, bn1w, bn1b, dinv, nullptr, nullptr,
        nullptr, nullptr, nullptr, nullptr, nullptr, nullptr, 1 << 30);
    k_gcn_aggr<<<aggr_blocks, 512, 0, stream>>>(h2b, offs, deg, csr, dinv,
                                                bgcn, bn2w, bn2b, wgate,
                                                bgate, wfc, gate, fcdot, N);
    k_pool<<<64, 256, 0, stream>>>(gate, fcdot, batch, bfc, out, N);
}